// Round 14
// baseline (1884.027 us; speedup 1.0000x reference)
//
#include <hip/hip_runtime.h>
#include <hip/hip_bf16.h>
#include <stdint.h>

#define NB 8
#define NN 8192
#define NC 64
#define NS 2048
#define NK 32
#define NCOL (NB*NS*NK)   // 524288 columns (b,s,n)

typedef float v2f __attribute__((ext_vector_type(2)));
typedef __attribute__((ext_vector_type(8))) short bf16x8;   // 8 bf16 (4 VGPRs)
typedef __attribute__((ext_vector_type(4))) float f32x4;    // MFMA acc

// ---------- bf16 helpers (RNE) ----------
__device__ __forceinline__ unsigned short f2bf(float x) {
    union { float f; unsigned u; } c; c.f = x;
    unsigned r = c.u + 0x7fffu + ((c.u >> 16) & 1u);
    return (unsigned short)(r >> 16);
}
__device__ __forceinline__ float bf2f(unsigned v16) {
    union { float f; unsigned u; } c; c.u = v16 << 16;
    return c.f;
}

// ---------- DPP cross-lane helpers (VALU-speed, no LDS) ----------
// row_shr:n = 0x110|n, row_bcast15 = 0x142, row_bcast31 = 0x143
template<int CTRL>
__device__ __forceinline__ unsigned long long dpp_max_u64(unsigned long long key) {
    int olo = __builtin_amdgcn_update_dpp(0, (int)(unsigned)key,        CTRL, 0xf, 0xf, true);
    int ohi = __builtin_amdgcn_update_dpp(0, (int)(unsigned)(key >> 32), CTRL, 0xf, 0xf, true);
    unsigned long long ok = ((unsigned long long)(unsigned)ohi << 32) | (unsigned)olo;
    return ok > key ? ok : key;   // zero-fill loses to every real key
}
template<int CTRL>
__device__ __forceinline__ float dpp_add_f32(float x) {   // zero-fill identity
    int o = __builtin_amdgcn_update_dpp(0, __float_as_int(x), CTRL, 0xf, 0xf, true);
    return x + __int_as_float(o);
}
template<int CTRL>
__device__ __forceinline__ float dpp_max_f32(float x) {   // self identity
    int o = __builtin_amdgcn_update_dpp(__float_as_int(x), __float_as_int(x), CTRL, 0xf, 0xf, false);
    return fmaxf(x, __int_as_float(o));
}
template<int CTRL>
__device__ __forceinline__ float dpp_min_f32(float x) {   // self identity
    int o = __builtin_amdgcn_update_dpp(__float_as_int(x), __float_as_int(x), CTRL, 0xf, 0xf, false);
    return fminf(x, __int_as_float(o));
}
template<int CTRL, int RM>
__device__ __forceinline__ unsigned dpp_add_u32(unsigned x) {  // zero-fill, row-masked
    int o = __builtin_amdgcn_update_dpp(0, (int)x, CTRL, RM, 0xf, true);
    return x + (unsigned)o;
}
__device__ __forceinline__ float wave_red_min(float x) {  // full 64-lane min -> all lanes
    x = dpp_min_f32<0x111>(x); x = dpp_min_f32<0x112>(x);
    x = dpp_min_f32<0x114>(x); x = dpp_min_f32<0x118>(x);
    x = dpp_min_f32<0x142>(x); x = dpp_min_f32<0x143>(x);
    return __int_as_float(__builtin_amdgcn_readlane(__float_as_int(x), 63));
}
__device__ __forceinline__ float wave_red_max(float x) {  // full 64-lane max -> all lanes
    x = dpp_max_f32<0x111>(x); x = dpp_max_f32<0x112>(x);
    x = dpp_max_f32<0x114>(x); x = dpp_max_f32<0x118>(x);
    x = dpp_max_f32<0x142>(x); x = dpp_max_f32<0x143>(x);
    return __int_as_float(__builtin_amdgcn_readlane(__float_as_int(x), 63));
}
__device__ __forceinline__ v2f relu2(v2f v) {
    v.x = fmaxf(v.x, 0.f); v.y = fmaxf(v.y, 0.f); return v;
}

// ============================================================================
// 0) Spatial partition: counting sort on top-11 Morton bits (2048 buckets).
//    Any permutation is CORRECT (ordering only affects pruning rate); FPS
//    tie-breaking uses original indices. Proven in R2/R5-R13.
// ============================================================================
__device__ __forceinline__ unsigned expand_bits10(unsigned v) {
    v = (v * 0x00010001u) & 0xFF0000FFu;
    v = (v * 0x00000101u) & 0x0F00F00Fu;
    v = (v * 0x00000011u) & 0xC30C30C3u;
    v = (v * 0x00000005u) & 0x49249249u;
    return v;
}
__global__ __launch_bounds__(1024) void sort_kernel(const float* __restrict__ xyz,
    float4* __restrict__ sorted)
{
    __shared__ unsigned cnt[2048];     // bucket counts -> start offsets
    __shared__ unsigned codes[NN];     // bucket id per point (32 KB)
    __shared__ unsigned wsum[16];
    const int b = blockIdx.x;
    const int tid = threadIdx.x;
    const int w = tid >> 6;
    const int lane = tid & 63;
    const float* xb = xyz + (size_t)b * NN * 3;
    cnt[tid] = 0; cnt[tid + 1024] = 0;
    __syncthreads();
    for (int p = tid; p < NN; p += 1024) {
        float x = xb[3*p+0], y = xb[3*p+1], z = xb[3*p+2];
        int qx = (int)(x * 1024.f); qx = qx < 0 ? 0 : (qx > 1023 ? 1023 : qx);
        int qy = (int)(y * 1024.f); qy = qy < 0 ? 0 : (qy > 1023 ? 1023 : qy);
        int qz = (int)(z * 1024.f); qz = qz < 0 ? 0 : (qz > 1023 ? 1023 : qz);
        unsigned m = expand_bits10((unsigned)qx)
                   | (expand_bits10((unsigned)qy) << 1)
                   | (expand_bits10((unsigned)qz) << 2);
        unsigned bk = m >> 19;                 // top 11 of 30 bits
        codes[p] = bk;
        atomicAdd(&cnt[bk], 1u);
    }
    __syncthreads();
    // exclusive scan of 2048 counts: thread t owns pair (2t, 2t+1)
    unsigned c0 = cnt[2*tid], c1 = cnt[2*tid+1];
    unsigned s = c0 + c1;
    unsigned v = s;                            // wave64 inclusive scan (canonical DPP)
    v = dpp_add_u32<0x111, 0xf>(v);
    v = dpp_add_u32<0x112, 0xf>(v);
    v = dpp_add_u32<0x114, 0xf>(v);
    v = dpp_add_u32<0x118, 0xf>(v);
    v = dpp_add_u32<0x142, 0xa>(v);            // bcast15 -> rows 1,3
    v = dpp_add_u32<0x143, 0xc>(v);            // bcast31 -> rows 2,3
    if (lane == 63) wsum[w] = v;
    __syncthreads();
    unsigned wbase = 0;
#pragma unroll
    for (int j = 0; j < 15; ++j) {             // exclusive prefix of wave totals
        unsigned t = wsum[j];
        wbase += (j < w) ? t : 0u;
    }
    unsigned excl = wbase + v - s;             // global exclusive prefix for bucket 2t
    cnt[2*tid]   = excl;                       // each thread touches only its own pair
    cnt[2*tid+1] = excl + c0;
    __syncthreads();
    // scatter
    for (int p = tid; p < NN; p += 1024) {
        unsigned bk = codes[p];
        unsigned pos = atomicAdd(&cnt[bk], 1u);
        float4 o;
        o.x = xb[3*p+0]; o.y = xb[3*p+1]; o.z = xb[3*p+2];
        o.w = __int_as_float(p);
        sorted[(size_t)b * NN + pos] = o;
    }
}

// ============================================================================
// 1) FPS (blocks 0..7, R9 version verbatim) FUSED with the feature transpose
//    (blocks 8..263) — proven in R13 (fps_tr = 1345 us, transpose rides on
//    the ~248 CUs that idle during fps's serial phase).
//    FPS: 16 waves x 512-pt chunks, bbox prune, monolithic u64 DPP reduce,
//    LDS atomicMax merge, ONE barrier/iter. Bit-exact (same key order,
//    3-slot rotation safety proven in R9).
// ============================================================================
__global__ __launch_bounds__(1024) void fps_tr_kernel(const float* __restrict__ xyz,
    const float4* __restrict__ sorted,
    float* __restrict__ new_xyz, float* __restrict__ out_newxyz,
    const float* __restrict__ feat, float* __restrict__ ft)
{
#pragma clang fp contract(off)
    const int tid = threadIdx.x;
    __shared__ float sx[NN], sy[NN], sz[NN];             // 96 KB, indexed by ORIG idx
    __shared__ float s_hist[NS * 3];                     // 24 KB selected-coord history
    __shared__ unsigned long long s_slot[3];             // rotating merge slots

    if (blockIdx.x >= NB) {
        // ---------------- transpose path: 4 tiles of 64x64 per block -------
        float* tbuf = sx;                                // 64*65 floats = 16.6 KB
        const int base = ((int)blockIdx.x - NB) * 4;
        for (int j = 0; j < 4; ++j) {
            const int t = base + j;                      // 0..1023
            const int b = t >> 7;                        // 128 tiles per batch
            const int p0 = (t & 127) << 6;
            for (int k = tid; k < 4096; k += 1024) {
                int c = k >> 6, p = k & 63;
                tbuf[c * 65 + p] = feat[((size_t)b * NC + c) * NN + p0 + p];
            }
            __syncthreads();
            for (int k = tid; k < 4096; k += 1024) {
                int p = k >> 6, c = k & 63;
                ft[((size_t)b * NN + p0 + p) * NC + c] = tbuf[c * 65 + p];
            }
            __syncthreads();
        }
        return;
    }

    // ---------------- fps path (R9 verbatim) -------------------------------
    const int b = blockIdx.x;
    const int w = tid >> 6;
    const int lane = tid & 63;
    const float4* sp = sorted + (size_t)b * NN + (size_t)w * 512 + lane;
    v2f px[4], py[4], pz[4], dmin[4];
    unsigned plo[8];                                     // ~orig_idx per point
    float bnx = 1e30f, bny = 1e30f, bnz = 1e30f;
    float bxx = -1e30f, bxy = -1e30f, bxz = -1e30f;
#pragma unroll
    for (int m = 0; m < 4; ++m) {
        float4 a = sp[128*m];                            // point k=2m
        float4 c = sp[128*m + 64];                       // point k=2m+1
        px[m].x = a.x; px[m].y = c.x;
        py[m].x = a.y; py[m].y = c.y;
        pz[m].x = a.z; pz[m].y = c.z;
        dmin[m].x = 1e10f; dmin[m].y = 1e10f;
        int ia = __float_as_int(a.w), ic = __float_as_int(c.w);
        plo[2*m]   = ~(unsigned)ia;
        plo[2*m+1] = ~(unsigned)ic;
        sx[ia] = a.x; sy[ia] = a.y; sz[ia] = a.z;        // scatter by orig idx
        sx[ic] = c.x; sy[ic] = c.y; sz[ic] = c.z;
        bnx = fminf(bnx, fminf(a.x, c.x)); bxx = fmaxf(bxx, fmaxf(a.x, c.x));
        bny = fminf(bny, fminf(a.y, c.y)); bxy = fmaxf(bxy, fmaxf(a.y, c.y));
        bnz = fminf(bnz, fminf(a.z, c.z)); bxz = fmaxf(bxz, fmaxf(a.z, c.z));
    }
    // wave bbox (uniform across the wave after readlane-broadcast)
    bnx = wave_red_min(bnx); bny = wave_red_min(bny); bnz = wave_red_min(bnz);
    bxx = wave_red_max(bxx); bxy = wave_red_max(bxy); bxz = wave_red_max(bxz);

    const float* xb = xyz + (size_t)b * NN * 3;
    float lx = xb[0], ly = xb[1], lz = xb[2];            // selection 0 = point 0
    if (tid == 0) {
        s_hist[0] = lx; s_hist[1] = ly; s_hist[2] = lz;
        s_slot[0] = 0ull; s_slot[1] = 0ull; s_slot[2] = 0ull;
    }
    float ckv = 1e30f;                                   // cached wave max dmin (forces 1st compute)
    unsigned cklo = 0u;                                  // cached tie-winner ~orig_idx
    __syncthreads();                                     // sx/sy/sz + slots + hist[0] visible

    int cur = 1, nxt = 2;                                // cur = i%3, nxt = (i+1)%3 at i=1
    for (int i = 1; i < NS; ++i) {
        if (tid == 0) s_slot[nxt] = 0ull;                // reset future slot (safe window)
        // certified fp32 lower bound of d_new for every point in this chunk
        float cdx = fmaxf(fmaxf(bnx - lx, lx - bxx), 0.f);
        float cdy = fmaxf(fmaxf(bny - ly, ly - bxy), 0.f);
        float cdz = fmaxf(fmaxf(bnz - lz, lz - bxz), 0.f);
        float lb = (cdx*cdx + cdy*cdy) + cdz*cdz;
        if (!(lb >= ckv)) {                              // wave-uniform branch
            v2f l2x; l2x.x = lx; l2x.y = lx;
            v2f l2y; l2y.x = ly; l2y.y = ly;
            v2f l2z; l2z.x = lz; l2z.y = lz;
            unsigned long long best = 0ull;
#pragma unroll
            for (int m = 0; m < 4; ++m) {
                v2f dx = px[m] - l2x;
                v2f dy = py[m] - l2y;
                v2f dz = pz[m] - l2z;
                v2f d = (dx*dx + dy*dy) + dz*dz;         // pk mul/add, exact order
                v2f dm;
                dm.x = fminf(dmin[m].x, d.x);
                dm.y = fminf(dmin[m].y, d.y);
                dmin[m] = dm;
                unsigned long long k0 =
                    ((unsigned long long)__float_as_uint(dm.x) << 32) | plo[2*m];
                unsigned long long k1 =
                    ((unsigned long long)__float_as_uint(dm.y) << 32) | plo[2*m+1];
                if (k0 > best) best = k0;
                if (k1 > best) best = k1;
            }
            // MONOLITHIC DPP wave64 max-reduce -> lane 63, broadcast via readlane
            best = dpp_max_u64<0x111>(best);
            best = dpp_max_u64<0x112>(best);
            best = dpp_max_u64<0x114>(best);
            best = dpp_max_u64<0x118>(best);
            best = dpp_max_u64<0x142>(best);
            best = dpp_max_u64<0x143>(best);
            ckv  = __uint_as_float((unsigned)__builtin_amdgcn_readlane((int)(best >> 32), 63));
            cklo = (unsigned)__builtin_amdgcn_readlane((int)(best & 0xffffffffull), 63);
        }
        if (lane == 0)
            atomicMax(&s_slot[cur],
                      ((unsigned long long)__float_as_uint(ckv) << 32) | cklo);
        __syncthreads();                                 // the ONLY barrier per iter
        const unsigned long long k = s_slot[cur];        // b64 broadcast read
        const int ix = ~(int)(unsigned)(k & 0xffffffffull);  // original point index
        lx = sx[ix]; ly = sy[ix]; lz = sz[ix];           // LDS broadcast gather
        if (tid == 0) {
            s_hist[3*i+0] = lx; s_hist[3*i+1] = ly; s_hist[3*i+2] = lz;
        }
        cur = nxt;                                       // rotate slot indices
        nxt = nxt + 1; if (nxt == 3) nxt = 0;
    }
    __syncthreads();                                     // last hist write visible
    // coalesced flush of the selected-coordinate history
    float* nw = new_xyz + (size_t)b * NS * 3;
    float* ow = out_newxyz + (size_t)b * NS * 3;
    for (int t = tid; t < NS * 3; t += 1024) {
        float v = s_hist[t];
        nw[t] = v; ow[t] = v;
    }
}

// ============================================================================
// 3) Ball query: one wave per (b,s) query. First 32 smallest in-ball indices,
//    pad with first. r2 must be float(0.2*0.2) = 0.0399999991 (not 0.2f*0.2f).
// ============================================================================
__global__ __launch_bounds__(256) void ballquery_kernel(const float* __restrict__ xyz,
    const float* __restrict__ new_xyz, int* __restrict__ idx)
{
#pragma clang fp contract(off)
    const int q = blockIdx.x * 4 + (threadIdx.x >> 6);
    const int lane = threadIdx.x & 63;
    const int b = q >> 11;
    const float r2 = (float)(0.2 * 0.2);
    const float* xb = xyz + (size_t)b * NN * 3;
    const float* nx = new_xyz + (size_t)q * 3;
    float qx = nx[0], qy = nx[1], qz = nx[2];
    int cnt = 0, first = -1;
    int* out = idx + (size_t)q * NK;
    for (int base = 0; base < NN; base += 64) {
        int p = base + lane;
        float x = xb[p*3+0], y = xb[p*3+1], z = xb[p*3+2];
        float dx = qx - x, dy = qy - y, dz = qz - z;
        float d2 = (dx*dx + dy*dy) + dz*dz;
        bool in = d2 < r2;
        unsigned long long m = __ballot(in);
        if (m) {
            if (first < 0) first = base + __builtin_ctzll(m);
            if (in) {
                int rank = cnt + __popcll(m & ((1ull << lane) - 1ull));
                if (rank < NK) out[rank] = p;
            }
            cnt += __popcll(m);
            if (cnt >= NK) break;
        }
    }
    for (int k = cnt + lane; k < NK; k += 64) out[k] = first;  // cnt>=1 always
}

// ============================================================================
// 4) Layer 1 + FUSED stats1: h1 = W1(64x67) @ g (fp32 packed FMAs, bf16
//    store) and, while the rounded values are live, per-channel sum/sumsq
//    via wave DPP reduce (a wave's 64 lanes hold the same channel for 64
//    different columns) -> lane63 LDS atomics -> block-end global atomics.
//    Same proven pattern as layer2/layer3's fused stats; removes the 67 MB
//    stats1 re-read pass. Stats computed on the ROUNDED stored values
//    (exactly what the old pass read); only f32 sum order differs.
// ============================================================================
__global__ __launch_bounds__(256, 2) void layer1_kernel(const float* __restrict__ xyz,
    const float* __restrict__ new_xyz, const int* __restrict__ idx,
    const float* __restrict__ ft, const float* __restrict__ W1,
    unsigned short* __restrict__ h1, float* __restrict__ sums1)
{
    __shared__ float ls[64], lq[64];
    const int tid = threadIdx.x;
    const int lane = tid & 63;
    if (tid < 64) { ls[tid] = 0.f; lq[tid] = 0.f; }
    __syncthreads();
    const int col = blockIdx.x * 256 + tid;
    const int b = col >> 16;
    const int s = (col >> 5) & 2047;
    const int p = idx[col];
    v2f g[34];
    float* gf = (float*)g;
    {
        const float* nx = new_xyz + ((size_t)(b * NS + s)) * 3;
        const float* xp = xyz + ((size_t)(b * NN + p)) * 3;
        gf[0] = xp[0] - nx[0]; gf[1] = xp[1] - nx[1]; gf[2] = xp[2] - nx[2];
    }
    const float4* fp = (const float4*)(ft + ((size_t)(b * NN + p)) * NC);
#pragma unroll
    for (int c4 = 0; c4 < 16; ++c4) {
        float4 v = fp[c4];
        gf[3 + 4*c4 + 0] = v.x; gf[3 + 4*c4 + 1] = v.y;
        gf[3 + 4*c4 + 2] = v.z; gf[3 + 4*c4 + 3] = v.w;
    }
    gf[67] = 0.f;
    uint4* dst = (uint4*)(h1 + (size_t)col * 64);
#pragma unroll
    for (int half = 0; half < 2; ++half) {
        float h[32];
#pragma unroll 4
        for (int o16 = 0; o16 < 32; ++o16) {
            const float* w = W1 + (half*32 + o16) * 67;
            v2f acc; acc.x = 0.f; acc.y = 0.f;
#pragma unroll
            for (int k = 0; k < 33; ++k) {
                v2f wv; wv.x = w[2*k]; wv.y = w[2*k+1];
                acc = wv * g[k] + acc;                    // v_pk_fma_f32
            }
            h[o16] = fmaf(w[66], gf[66], acc.x + acc.y);
        }
#pragma unroll
        for (int k = 0; k < 4; ++k) {
            unsigned u[8];
#pragma unroll
            for (int j = 0; j < 8; ++j) u[j] = f2bf(h[8*k+j]);
            uint4 v;
            v.x = u[0] | (u[1] << 16); v.y = u[2] | (u[3] << 16);
            v.z = u[4] | (u[5] << 16); v.w = u[6] | (u[7] << 16);
            dst[half*4 + k] = v;
            // fused stats on the rounded values: wave-reduce over 64 columns
#pragma unroll
            for (int j = 0; j < 8; ++j) {
                float vv = bf2f(u[j]);
                float sm = vv, sq = vv * vv;
                sm = dpp_add_f32<0x111>(sm); sq = dpp_add_f32<0x111>(sq);
                sm = dpp_add_f32<0x112>(sm); sq = dpp_add_f32<0x112>(sq);
                sm = dpp_add_f32<0x114>(sm); sq = dpp_add_f32<0x114>(sq);
                sm = dpp_add_f32<0x118>(sm); sq = dpp_add_f32<0x118>(sq);
                sm = dpp_add_f32<0x142>(sm); sq = dpp_add_f32<0x142>(sq);
                sm = dpp_add_f32<0x143>(sm); sq = dpp_add_f32<0x143>(sq);
                if (lane == 63) {
                    const int ch = half * 32 + 8 * k + j;
                    atomicAdd(&ls[ch], sm);
                    atomicAdd(&lq[ch], sq);
                }
            }
        }
    }
    __syncthreads();
    if (tid < 64) {
        atomicAdd(&sums1[tid*2+0], ls[tid]);
        atomicAdd(&sums1[tid*2+1], lq[tid]);
    }
}

// ============================================================================
// 6) Finalize BN params. Layout: ab[c] = a_c (scale), ab[nch+c] = b_c (shift)
//    so the apply step can use packed v2f math.
// ============================================================================
__global__ void finalize_kernel(const float* __restrict__ sums,
    const float* __restrict__ gamma, const float* __restrict__ beta,
    float* __restrict__ ab, int nch)
{
    int c = threadIdx.x;
    if (c < nch) {
        const float invM = 1.0f / 524288.0f;
        float mu = sums[c*2] * invM;
        float var = sums[c*2+1] * invM - mu * mu;
        float a = gamma[c] / sqrtf(var + 1e-5f);
        ab[c] = a;
        ab[nch + c] = fmaf(-mu, a, beta[c]);
    }
}

// ============================================================================
// 7) Layer 2 via MFMA + FUSED stats2 (R13, proven): h2 = W2 @ relu(BN1(h1)),
//    stats of the ROUNDED stored values accumulated in the epilogue.
// ============================================================================
__global__ __launch_bounds__(256, 2) void layer2_kernel(const unsigned short* __restrict__ h1,
    const float* __restrict__ ab1, const float* __restrict__ W2,
    unsigned short* __restrict__ h2, float* __restrict__ sums2)
{
    __shared__ float ls[64], lq[64];
    const int tid = threadIdx.x;
    if (tid < 64) { ls[tid] = 0.f; lq[tid] = 0.f; }
    __syncthreads();
    const int lane = tid & 63;
    const int col0 = lane & 15;                          // n (col in tile) / m (row of A)
    const int rg   = lane >> 4;                          // k-group (inputs), row-group (D)
    const int wglob = blockIdx.x * 4 + (tid >> 6);       // 0..8191

    float sums[16], sqs[16];                             // [rt*4 + r]
#pragma unroll
    for (int t = 0; t < 16; ++t) { sums[t] = 0.f; sqs[t] = 0.f; }

    for (int g = wglob * 2; g < wglob * 2 + 2; ++g) {    // 2 (b,s)-groups per wave
        // ---- build B fragments for both 16-col tiles of this group ----
        bf16x8 Bf[2][2];                                 // [tile][kh]
#pragma unroll
        for (int t = 0; t < 2; ++t) {
            const int col = g * 32 + t * 16 + col0;
            const unsigned short* hp = h1 + (size_t)col * 64 + rg * 8;
#pragma unroll
            for (int kh = 0; kh < 2; ++kh) {
                uint4 hv = *(const uint4*)(hp + kh * 32);
                const float* ap = ab1 + kh * 32 + rg * 8;
                float4 a0 = *(const float4*)ap;
                float4 a1 = *(const float4*)(ap + 4);
                float4 b0 = *(const float4*)(ap + 64);
                float4 b1 = *(const float4*)(ap + 68);
                bf16x8 f;
                f[0] = (short)f2bf(fmaxf(fmaf(a0.x, bf2f(hv.x & 0xffffu), b0.x), 0.f));
                f[1] = (short)f2bf(fmaxf(fmaf(a0.y, bf2f(hv.x >> 16),     b0.y), 0.f));
                f[2] = (short)f2bf(fmaxf(fmaf(a0.z, bf2f(hv.y & 0xffffu), b0.z), 0.f));
                f[3] = (short)f2bf(fmaxf(fmaf(a0.w, bf2f(hv.y >> 16),     b0.w), 0.f));
                f[4] = (short)f2bf(fmaxf(fmaf(a1.x, bf2f(hv.z & 0xffffu), b1.x), 0.f));
                f[5] = (short)f2bf(fmaxf(fmaf(a1.y, bf2f(hv.z >> 16),     b1.y), 0.f));
                f[6] = (short)f2bf(fmaxf(fmaf(a1.z, bf2f(hv.w & 0xffffu), b1.z), 0.f));
                f[7] = (short)f2bf(fmaxf(fmaf(a1.w, bf2f(hv.w >> 16),     b1.w), 0.f));
                Bf[t][kh] = f;
            }
        }
        // ---- 4 row-tiles of 16 output channels (64 outputs total) ----
#pragma unroll
        for (int rt = 0; rt < 4; ++rt) {
            f32x4 acc0 = {0.f, 0.f, 0.f, 0.f};
            f32x4 acc1 = {0.f, 0.f, 0.f, 0.f};
#pragma unroll
            for (int kh = 0; kh < 2; ++kh) {
                const float* wp = W2 + (size_t)(rt * 16 + col0) * 64 + kh * 32 + rg * 8;
                float4 w0 = *(const float4*)wp;
                float4 w1 = *(const float4*)(wp + 4);
                bf16x8 Af;
                Af[0] = (short)f2bf(w0.x); Af[1] = (short)f2bf(w0.y);
                Af[2] = (short)f2bf(w0.z); Af[3] = (short)f2bf(w0.w);
                Af[4] = (short)f2bf(w1.x); Af[5] = (short)f2bf(w1.y);
                Af[6] = (short)f2bf(w1.z); Af[7] = (short)f2bf(w1.w);
                acc0 = __builtin_amdgcn_mfma_f32_16x16x32_bf16(Af, Bf[0][kh], acc0, 0, 0, 0);
                acc1 = __builtin_amdgcn_mfma_f32_16x16x32_bf16(Af, Bf[1][kh], acc1, 0, 0, 0);
            }
            // store rounded bf16 + accumulate stats of the ROUNDED values
            unsigned u00 = f2bf(acc0[0]), u01 = f2bf(acc0[1]);
            unsigned u02 = f2bf(acc0[2]), u03 = f2bf(acc0[3]);
            unsigned u10 = f2bf(acc1[0]), u11 = f2bf(acc1[1]);
            unsigned u12 = f2bf(acc1[2]), u13 = f2bf(acc1[3]);
            {
                const int col = g * 32 + 0 * 16 + col0;
                uint2 v; v.x = u00 | (u01 << 16); v.y = u02 | (u03 << 16);
                *(uint2*)(h2 + (size_t)col * 64 + rt * 16 + rg * 4) = v;
            }
            {
                const int col = g * 32 + 1 * 16 + col0;
                uint2 v; v.x = u10 | (u11 << 16); v.y = u12 | (u13 << 16);
                *(uint2*)(h2 + (size_t)col * 64 + rt * 16 + rg * 4) = v;
            }
#pragma unroll
            for (int r = 0; r < 4; ++r) {
                float r0 = bf2f(r == 0 ? u00 : r == 1 ? u01 : r == 2 ? u02 : u03);
                float r1 = bf2f(r == 0 ? u10 : r == 1 ? u11 : r == 2 ? u12 : u13);
                sums[rt*4 + r] += r0 + r1;
                sqs[rt*4 + r]  = fmaf(r0, r0, fmaf(r1, r1, sqs[rt*4 + r]));
            }
        }
    }
    // ---- channel sums: reduce over cols (16-lane rows), then LDS -> global
#pragma unroll
    for (int t = 0; t < 16; ++t) {
        float sm = sums[t], sq = sqs[t];
        sm = dpp_add_f32<0x111>(sm); sq = dpp_add_f32<0x111>(sq);
        sm = dpp_add_f32<0x112>(sm); sq = dpp_add_f32<0x112>(sq);
        sm = dpp_add_f32<0x114>(sm); sq = dpp_add_f32<0x114>(sq);
        sm = dpp_add_f32<0x118>(sm); sq = dpp_add_f32<0x118>(sq);
        if (col0 == 15) {
            const int o = (t >> 2) * 16 + rg * 4 + (t & 3);
            atomicAdd(&ls[o], sm);
            atomicAdd(&lq[o], sq);
        }
    }
    __syncthreads();
    if (tid < 64) {
        atomicAdd(&sums2[tid*2+0], ls[tid]);
        atomicAdd(&sums2[tid*2+1], lq[tid]);
    }
}

// ============================================================================
// 8) Layer 3 via MFMA (bf16 in, f32 acc): h3 = W3(128x64) @ relu(BN2(h2)).
//    R10/R11 version (proven).
// ============================================================================
__global__ __launch_bounds__(256, 2) void layer3_kernel(const unsigned short* __restrict__ h2,
    const float* __restrict__ ab2, const float* __restrict__ W3,
    float* __restrict__ hmax, float* __restrict__ hmin, float* __restrict__ sums3)
{
    __shared__ float ls[128], lq[128];
    const int tid = threadIdx.x;
    if (tid < 128) { ls[tid] = 0.f; lq[tid] = 0.f; }
    __syncthreads();
    const int lane = tid & 63;
    const int col0 = lane & 15;                          // n (col in tile) / m (row of A)
    const int rg   = lane >> 4;                          // k-group (inputs), row-group (D)
    const int wglob = blockIdx.x * 4 + (tid >> 6);       // 0..8191

    float sums[32], sqs[32];                             // [rt][reg]
#pragma unroll
    for (int t = 0; t < 32; ++t) { sums[t] = 0.f; sqs[t] = 0.f; }

    for (int g = wglob * 2; g < wglob * 2 + 2; ++g) {    // 2 (b,s)-groups per wave
        // ---- build B fragments for both 16-col tiles of this group ----
        bf16x8 Bf[2][2];                                 // [tile][kh]
#pragma unroll
        for (int t = 0; t < 2; ++t) {
            const int col = g * 32 + t * 16 + col0;
            const unsigned short* hp = h2 + (size_t)col * 64 + rg * 8;
#pragma unroll
            for (int kh = 0; kh < 2; ++kh) {
                uint4 hv = *(const uint4*)(hp + kh * 32);
                const float* ap = ab2 + kh * 32 + rg * 8;
                float4 a0 = *(const float4*)ap;
                float4 a1 = *(const float4*)(ap + 4);
                float4 b0 = *(const float4*)(ap + 64);
                float4 b1 = *(const float4*)(ap + 68);
                bf16x8 f;
                f[0] = (short)f2bf(fmaxf(fmaf(a0.x, bf2f(hv.x & 0xffffu), b0.x), 0.f));
                f[1] = (short)f2bf(fmaxf(fmaf(a0.y, bf2f(hv.x >> 16),     b0.y), 0.f));
                f[2] = (short)f2bf(fmaxf(fmaf(a0.z, bf2f(hv.y & 0xffffu), b0.z), 0.f));
                f[3] = (short)f2bf(fmaxf(fmaf(a0.w, bf2f(hv.y >> 16),     b0.w), 0.f));
                f[4] = (short)f2bf(fmaxf(fmaf(a1.x, bf2f(hv.z & 0xffffu), b1.x), 0.f));
                f[5] = (short)f2bf(fmaxf(fmaf(a1.y, bf2f(hv.z >> 16),     b1.y), 0.f));
                f[6] = (short)f2bf(fmaxf(fmaf(a1.z, bf2f(hv.w & 0xffffu), b1.z), 0.f));
                f[7] = (short)f2bf(fmaxf(fmaf(a1.w, bf2f(hv.w >> 16),     b1.w), 0.f));
                Bf[t][kh] = f;
            }
        }
        // ---- 8 row-tiles of 16 output channels ----
#pragma unroll
        for (int rt = 0; rt < 8; ++rt) {
            f32x4 acc0 = {0.f, 0.f, 0.f, 0.f};
            f32x4 acc1 = {0.f, 0.f, 0.f, 0.f};
#pragma unroll
            for (int kh = 0; kh < 2; ++kh) {
                const float* wp = W3 + (size_t)(rt * 16 + col0) * 64 + kh * 32 + rg * 8;
                float4 w0 = *(const float4*)wp;
                float4 w1 = *(const float4*)(wp + 4);
                bf16x8 Af;
                Af[0] = (short)f2bf(w0.x); Af[1] = (short)f2bf(w0.y);
                Af[2] = (short)f2bf(w0.z); Af[3] = (short)f2bf(w0.w);
                Af[4] = (short)f2bf(w1.x); Af[5] = (short)f2bf(w1.y);
                Af[6] = (short)f2bf(w1.z); Af[7] = (short)f2bf(w1.w);
                acc0 = __builtin_amdgcn_mfma_f32_16x16x32_bf16(Af, Bf[0][kh], acc0, 0, 0, 0);
                acc1 = __builtin_amdgcn_mfma_f32_16x16x32_bf16(Af, Bf[1][kh], acc1, 0, 0, 0);
            }
#pragma unroll
            for (int r = 0; r < 4; ++r) {
                float v0 = acc0[r], v1 = acc1[r];
                sums[rt*4 + r] += v0 + v1;
                sqs[rt*4 + r]  = fmaf(v0, v0, fmaf(v1, v1, sqs[rt*4 + r]));
                float mx = fmaxf(v0, v1);
                float mn = fminf(v0, v1);
                mx = dpp_max_f32<0x111>(mx); mn = dpp_min_f32<0x111>(mn);
                mx = dpp_max_f32<0x112>(mx); mn = dpp_min_f32<0x112>(mn);
                mx = dpp_max_f32<0x114>(mx); mn = dpp_min_f32<0x114>(mn);
                mx = dpp_max_f32<0x118>(mx); mn = dpp_min_f32<0x118>(mn);
                if (col0 == 15) {                        // lane15 of each 16-lane row
                    const int o = rt * 16 + rg * 4 + r;
                    hmax[(size_t)o * 16384 + g] = mx;
                    hmin[(size_t)o * 16384 + g] = mn;
                }
            }
        }
    }
    // ---- channel sums: reduce over cols (16-lane rows), then LDS -> global
#pragma unroll
    for (int t = 0; t < 32; ++t) {
        float sm = sums[t], sq = sqs[t];
        sm = dpp_add_f32<0x111>(sm); sq = dpp_add_f32<0x111>(sq);
        sm = dpp_add_f32<0x112>(sm); sq = dpp_add_f32<0x112>(sq);
        sm = dpp_add_f32<0x114>(sm); sq = dpp_add_f32<0x114>(sq);
        sm = dpp_add_f32<0x118>(sm); sq = dpp_add_f32<0x118>(sq);
        if (col0 == 15) {
            const int o = (t >> 2) * 16 + rg * 4 + (t & 3);
            atomicAdd(&ls[o], sm);
            atomicAdd(&lq[o], sq);
        }
    }
    __syncthreads();
    if (tid < 128) {
        atomicAdd(&sums3[tid*2+0], ls[tid]);
        atomicAdd(&sums3[tid*2+1], lq[tid]);
    }
}

// ============================================================================
// 9) Final: feats[b,o,s] = relu(a3*(a3>=0 ? max : min) + c3)
// ============================================================================
__global__ __launch_bounds__(256) void final_kernel(const float* __restrict__ hmax,
    const float* __restrict__ hmin, const float* __restrict__ ab3,
    float* __restrict__ out)
{
    const int t = blockIdx.x * 256 + threadIdx.x;   // (b,o,s), s fastest
    const int s = t & 2047;
    const int o = (t >> 11) & 127;
    const int b = t >> 18;
    const int q = (b << 11) + s;
    float a = ab3[o], c = ab3[128 + o];
    float h = (a >= 0.f) ? hmax[(size_t)o * 16384 + q] : hmin[(size_t)o * 16384 + q];
    out[t] = fmaxf(fmaf(a, h, c), 0.f);
}

// ============================================================================
extern "C" void kernel_launch(void* const* d_in, const int* in_sizes, int n_in,
                              void* d_out, int out_size, void* d_ws, size_t ws_size,
                              hipStream_t stream) {
    (void)in_sizes; (void)n_in; (void)out_size; (void)ws_size;
    const float* xyz      = (const float*)d_in[0];
    const float* features = (const float*)d_in[1];
    const float* W1 = (const float*)d_in[2];
    const float* g1 = (const float*)d_in[3];
    const float* b1 = (const float*)d_in[4];
    const float* W2 = (const float*)d_in[5];
    const float* g2 = (const float*)d_in[6];
    const float* b2 = (const float*)d_in[7];
    const float* W3 = (const float*)d_in[8];
    const float* g3 = (const float*)d_in[9];
    const float* b3 = (const float*)d_in[10];

    char* ws = (char*)d_ws;
    float*          new_xyz = (float*)(ws + 0);                  // 196608 B
    int*            idx     = (int*)(ws + 196608);               // 2097152 B
    float*          ft      = (float*)(ws + 2293760);            // 16777216 B
    unsigned short* h1      = (unsigned short*)(ws + 19070976);  // 67108864 B
    unsigned short* h2      = (unsigned short*)(ws + 86179840);  // 67108864 B
    float*          hmax    = (float*)(ws + 153288704);          // 8388608 B
    float*          hmin    = (float*)(ws + 161677312);          // 8388608 B
    float*          sums    = (float*)(ws + 170065920);          // 2048 B (zeroed)
    float*          ab      = (float*)(ws + 170067968);          // 2048 B
    float* sums1 = sums;        float* ab1 = ab;
    float* sums2 = sums + 128;  float* ab2 = ab + 128;
    float* sums3 = sums + 256;  float* ab3 = ab + 256;

    // sorted point array (float4 x,y,z,idx) lives in h1's space: h1 is only
    // written by layer1 AFTER fps completes (stream order), so no conflict.
    float4* sorted = (float4*)h1;                 // NB*NN*16 = 1 MB

    float* out_newxyz = (float*)d_out;            // B*NS*3 = 49152 floats
    float* out_feats  = (float*)d_out + 49152;    // B*128*NS floats

    hipMemsetAsync(sums, 0, 2048, stream);

    sort_kernel<<<NB, 1024, 0, stream>>>(xyz, sorted);
    // fps (blocks 0-7) + transpose (blocks 8-263) fused
    fps_tr_kernel<<<NB + 256, 1024, 0, stream>>>(xyz, sorted, new_xyz, out_newxyz,
                                                 features, ft);
    ballquery_kernel<<<(NB*NS)/4, 256, 0, stream>>>(xyz, new_xyz, idx);
    layer1_kernel<<<NCOL/256, 256, 0, stream>>>(xyz, new_xyz, idx, ft, W1, h1, sums1); // stats1 fused
    finalize_kernel<<<1, 128, 0, stream>>>(sums1, g1, b1, ab1, 64);
    layer2_kernel<<<2048, 256, 0, stream>>>(h1, ab1, W2, h2, sums2);   // stats2 fused
    finalize_kernel<<<1, 128, 0, stream>>>(sums2, g2, b2, ab2, 64);
    layer3_kernel<<<2048, 256, 0, stream>>>(h2, ab2, W3, hmax, hmin, sums3);
    finalize_kernel<<<1, 128, 0, stream>>>(sums3, g3, b3, ab3, 128);
    final_kernel<<<(NB*128*NS)/256, 256, 0, stream>>>(hmax, hmin, ab3, out_feats);
}

// Round 15
// 1860.981 us; speedup vs baseline: 1.0124x; 1.0124x over previous
//
#include <hip/hip_runtime.h>
#include <hip/hip_bf16.h>
#include <stdint.h>

#define NB 8
#define NN 8192
#define NC 64
#define NS 2048
#define NK 32
#define NCOL (NB*NS*NK)   // 524288 columns (b,s,n)

typedef float v2f __attribute__((ext_vector_type(2)));
typedef __attribute__((ext_vector_type(8))) short bf16x8;   // 8 bf16 (4 VGPRs)
typedef __attribute__((ext_vector_type(4))) float f32x4;    // MFMA acc

// ---------- bf16 helpers (RNE) ----------
__device__ __forceinline__ unsigned short f2bf(float x) {
    union { float f; unsigned u; } c; c.f = x;
    unsigned r = c.u + 0x7fffu + ((c.u >> 16) & 1u);
    return (unsigned short)(r >> 16);
}
__device__ __forceinline__ float bf2f(unsigned v16) {
    union { float f; unsigned u; } c; c.u = v16 << 16;
    return c.f;
}

// ---------- DPP cross-lane helpers (VALU-speed, no LDS) ----------
// row_shr:n = 0x110|n, row_bcast15 = 0x142, row_bcast31 = 0x143
template<int CTRL>
__device__ __forceinline__ unsigned long long dpp_max_u64(unsigned long long key) {
    int olo = __builtin_amdgcn_update_dpp(0, (int)(unsigned)key,        CTRL, 0xf, 0xf, true);
    int ohi = __builtin_amdgcn_update_dpp(0, (int)(unsigned)(key >> 32), CTRL, 0xf, 0xf, true);
    unsigned long long ok = ((unsigned long long)(unsigned)ohi << 32) | (unsigned)olo;
    return ok > key ? ok : key;   // zero-fill loses to every real key
}
template<int CTRL>
__device__ __forceinline__ float dpp_add_f32(float x) {   // zero-fill identity
    int o = __builtin_amdgcn_update_dpp(0, __float_as_int(x), CTRL, 0xf, 0xf, true);
    return x + __int_as_float(o);
}
template<int CTRL>
__device__ __forceinline__ float dpp_max_f32(float x) {   // self identity
    int o = __builtin_amdgcn_update_dpp(__float_as_int(x), __float_as_int(x), CTRL, 0xf, 0xf, false);
    return fmaxf(x, __int_as_float(o));
}
template<int CTRL>
__device__ __forceinline__ float dpp_min_f32(float x) {   // self identity
    int o = __builtin_amdgcn_update_dpp(__float_as_int(x), __float_as_int(x), CTRL, 0xf, 0xf, false);
    return fminf(x, __int_as_float(o));
}
template<int CTRL, int RM>
__device__ __forceinline__ unsigned dpp_add_u32(unsigned x) {  // zero-fill, row-masked
    int o = __builtin_amdgcn_update_dpp(0, (int)x, CTRL, RM, 0xf, true);
    return x + (unsigned)o;
}
__device__ __forceinline__ float wave_red_min(float x) {  // full 64-lane min -> all lanes
    x = dpp_min_f32<0x111>(x); x = dpp_min_f32<0x112>(x);
    x = dpp_min_f32<0x114>(x); x = dpp_min_f32<0x118>(x);
    x = dpp_min_f32<0x142>(x); x = dpp_min_f32<0x143>(x);
    return __int_as_float(__builtin_amdgcn_readlane(__float_as_int(x), 63));
}
__device__ __forceinline__ float wave_red_max(float x) {  // full 64-lane max -> all lanes
    x = dpp_max_f32<0x111>(x); x = dpp_max_f32<0x112>(x);
    x = dpp_max_f32<0x114>(x); x = dpp_max_f32<0x118>(x);
    x = dpp_max_f32<0x142>(x); x = dpp_max_f32<0x143>(x);
    return __int_as_float(__builtin_amdgcn_readlane(__float_as_int(x), 63));
}
__device__ __forceinline__ v2f relu2(v2f v) {
    v.x = fmaxf(v.x, 0.f); v.y = fmaxf(v.y, 0.f); return v;
}

// ============================================================================
// 0) Spatial partition: counting sort on top-11 Morton bits (2048 buckets).
//    Any permutation is CORRECT (ordering only affects pruning rate); FPS
//    tie-breaking uses original indices. Proven in R2/R5-R14.
// ============================================================================
__device__ __forceinline__ unsigned expand_bits10(unsigned v) {
    v = (v * 0x00010001u) & 0xFF0000FFu;
    v = (v * 0x00000101u) & 0x0F00F00Fu;
    v = (v * 0x00000011u) & 0xC30C30C3u;
    v = (v * 0x00000005u) & 0x49249249u;
    return v;
}
__global__ __launch_bounds__(1024) void sort_kernel(const float* __restrict__ xyz,
    float4* __restrict__ sorted)
{
    __shared__ unsigned cnt[2048];     // bucket counts -> start offsets
    __shared__ unsigned codes[NN];     // bucket id per point (32 KB)
    __shared__ unsigned wsum[16];
    const int b = blockIdx.x;
    const int tid = threadIdx.x;
    const int w = tid >> 6;
    const int lane = tid & 63;
    const float* xb = xyz + (size_t)b * NN * 3;
    cnt[tid] = 0; cnt[tid + 1024] = 0;
    __syncthreads();
    for (int p = tid; p < NN; p += 1024) {
        float x = xb[3*p+0], y = xb[3*p+1], z = xb[3*p+2];
        int qx = (int)(x * 1024.f); qx = qx < 0 ? 0 : (qx > 1023 ? 1023 : qx);
        int qy = (int)(y * 1024.f); qy = qy < 0 ? 0 : (qy > 1023 ? 1023 : qy);
        int qz = (int)(z * 1024.f); qz = qz < 0 ? 0 : (qz > 1023 ? 1023 : qz);
        unsigned m = expand_bits10((unsigned)qx)
                   | (expand_bits10((unsigned)qy) << 1)
                   | (expand_bits10((unsigned)qz) << 2);
        unsigned bk = m >> 19;                 // top 11 of 30 bits
        codes[p] = bk;
        atomicAdd(&cnt[bk], 1u);
    }
    __syncthreads();
    // exclusive scan of 2048 counts: thread t owns pair (2t, 2t+1)
    unsigned c0 = cnt[2*tid], c1 = cnt[2*tid+1];
    unsigned s = c0 + c1;
    unsigned v = s;                            // wave64 inclusive scan (canonical DPP)
    v = dpp_add_u32<0x111, 0xf>(v);
    v = dpp_add_u32<0x112, 0xf>(v);
    v = dpp_add_u32<0x114, 0xf>(v);
    v = dpp_add_u32<0x118, 0xf>(v);
    v = dpp_add_u32<0x142, 0xa>(v);            // bcast15 -> rows 1,3
    v = dpp_add_u32<0x143, 0xc>(v);            // bcast31 -> rows 2,3
    if (lane == 63) wsum[w] = v;
    __syncthreads();
    unsigned wbase = 0;
#pragma unroll
    for (int j = 0; j < 15; ++j) {             // exclusive prefix of wave totals
        unsigned t = wsum[j];
        wbase += (j < w) ? t : 0u;
    }
    unsigned excl = wbase + v - s;             // global exclusive prefix for bucket 2t
    cnt[2*tid]   = excl;                       // each thread touches only its own pair
    cnt[2*tid+1] = excl + c0;
    __syncthreads();
    // scatter
    for (int p = tid; p < NN; p += 1024) {
        unsigned bk = codes[p];
        unsigned pos = atomicAdd(&cnt[bk], 1u);
        float4 o;
        o.x = xb[3*p+0]; o.y = xb[3*p+1]; o.z = xb[3*p+2];
        o.w = __int_as_float(p);
        sorted[(size_t)b * NN + pos] = o;
    }
}

// ============================================================================
// 1) FPS (blocks 0..7, R9 version verbatim) FUSED with the feature transpose
//    (blocks 8..263) — proven in R13 (fps_tr = 1345 us, transpose rides on
//    the ~248 CUs that idle during fps's serial phase).
//    FPS: 16 waves x 512-pt chunks, bbox prune, monolithic u64 DPP reduce,
//    LDS atomicMax merge, ONE barrier/iter. Bit-exact (same key order,
//    3-slot rotation safety proven in R9).
// ============================================================================
__global__ __launch_bounds__(1024) void fps_tr_kernel(const float* __restrict__ xyz,
    const float4* __restrict__ sorted,
    float* __restrict__ new_xyz, float* __restrict__ out_newxyz,
    const float* __restrict__ feat, float* __restrict__ ft)
{
#pragma clang fp contract(off)
    const int tid = threadIdx.x;
    __shared__ float sx[NN], sy[NN], sz[NN];             // 96 KB, indexed by ORIG idx
    __shared__ float s_hist[NS * 3];                     // 24 KB selected-coord history
    __shared__ unsigned long long s_slot[3];             // rotating merge slots

    if (blockIdx.x >= NB) {
        // ---------------- transpose path: 4 tiles of 64x64 per block -------
        float* tbuf = sx;                                // 64*65 floats = 16.6 KB
        const int base = ((int)blockIdx.x - NB) * 4;
        for (int j = 0; j < 4; ++j) {
            const int t = base + j;                      // 0..1023
            const int b = t >> 7;                        // 128 tiles per batch
            const int p0 = (t & 127) << 6;
            for (int k = tid; k < 4096; k += 1024) {
                int c = k >> 6, p = k & 63;
                tbuf[c * 65 + p] = feat[((size_t)b * NC + c) * NN + p0 + p];
            }
            __syncthreads();
            for (int k = tid; k < 4096; k += 1024) {
                int p = k >> 6, c = k & 63;
                ft[((size_t)b * NN + p0 + p) * NC + c] = tbuf[c * 65 + p];
            }
            __syncthreads();
        }
        return;
    }

    // ---------------- fps path (R9 verbatim) -------------------------------
    const int b = blockIdx.x;
    const int w = tid >> 6;
    const int lane = tid & 63;
    const float4* sp = sorted + (size_t)b * NN + (size_t)w * 512 + lane;
    v2f px[4], py[4], pz[4], dmin[4];
    unsigned plo[8];                                     // ~orig_idx per point
    float bnx = 1e30f, bny = 1e30f, bnz = 1e30f;
    float bxx = -1e30f, bxy = -1e30f, bxz = -1e30f;
#pragma unroll
    for (int m = 0; m < 4; ++m) {
        float4 a = sp[128*m];                            // point k=2m
        float4 c = sp[128*m + 64];                       // point k=2m+1
        px[m].x = a.x; px[m].y = c.x;
        py[m].x = a.y; py[m].y = c.y;
        pz[m].x = a.z; pz[m].y = c.z;
        dmin[m].x = 1e10f; dmin[m].y = 1e10f;
        int ia = __float_as_int(a.w), ic = __float_as_int(c.w);
        plo[2*m]   = ~(unsigned)ia;
        plo[2*m+1] = ~(unsigned)ic;
        sx[ia] = a.x; sy[ia] = a.y; sz[ia] = a.z;        // scatter by orig idx
        sx[ic] = c.x; sy[ic] = c.y; sz[ic] = c.z;
        bnx = fminf(bnx, fminf(a.x, c.x)); bxx = fmaxf(bxx, fmaxf(a.x, c.x));
        bny = fminf(bny, fminf(a.y, c.y)); bxy = fmaxf(bxy, fmaxf(a.y, c.y));
        bnz = fminf(bnz, fminf(a.z, c.z)); bxz = fmaxf(bxz, fmaxf(a.z, c.z));
    }
    // wave bbox (uniform across the wave after readlane-broadcast)
    bnx = wave_red_min(bnx); bny = wave_red_min(bny); bnz = wave_red_min(bnz);
    bxx = wave_red_max(bxx); bxy = wave_red_max(bxy); bxz = wave_red_max(bxz);

    const float* xb = xyz + (size_t)b * NN * 3;
    float lx = xb[0], ly = xb[1], lz = xb[2];            // selection 0 = point 0
    if (tid == 0) {
        s_hist[0] = lx; s_hist[1] = ly; s_hist[2] = lz;
        s_slot[0] = 0ull; s_slot[1] = 0ull; s_slot[2] = 0ull;
    }
    float ckv = 1e30f;                                   // cached wave max dmin (forces 1st compute)
    unsigned cklo = 0u;                                  // cached tie-winner ~orig_idx
    __syncthreads();                                     // sx/sy/sz + slots + hist[0] visible

    int cur = 1, nxt = 2;                                // cur = i%3, nxt = (i+1)%3 at i=1
    for (int i = 1; i < NS; ++i) {
        if (tid == 0) s_slot[nxt] = 0ull;                // reset future slot (safe window)
        // certified fp32 lower bound of d_new for every point in this chunk
        float cdx = fmaxf(fmaxf(bnx - lx, lx - bxx), 0.f);
        float cdy = fmaxf(fmaxf(bny - ly, ly - bxy), 0.f);
        float cdz = fmaxf(fmaxf(bnz - lz, lz - bxz), 0.f);
        float lb = (cdx*cdx + cdy*cdy) + cdz*cdz;
        if (!(lb >= ckv)) {                              // wave-uniform branch
            v2f l2x; l2x.x = lx; l2x.y = lx;
            v2f l2y; l2y.x = ly; l2y.y = ly;
            v2f l2z; l2z.x = lz; l2z.y = lz;
            unsigned long long best = 0ull;
#pragma unroll
            for (int m = 0; m < 4; ++m) {
                v2f dx = px[m] - l2x;
                v2f dy = py[m] - l2y;
                v2f dz = pz[m] - l2z;
                v2f d = (dx*dx + dy*dy) + dz*dz;         // pk mul/add, exact order
                v2f dm;
                dm.x = fminf(dmin[m].x, d.x);
                dm.y = fminf(dmin[m].y, d.y);
                dmin[m] = dm;
                unsigned long long k0 =
                    ((unsigned long long)__float_as_uint(dm.x) << 32) | plo[2*m];
                unsigned long long k1 =
                    ((unsigned long long)__float_as_uint(dm.y) << 32) | plo[2*m+1];
                if (k0 > best) best = k0;
                if (k1 > best) best = k1;
            }
            // MONOLITHIC DPP wave64 max-reduce -> lane 63, broadcast via readlane
            best = dpp_max_u64<0x111>(best);
            best = dpp_max_u64<0x112>(best);
            best = dpp_max_u64<0x114>(best);
            best = dpp_max_u64<0x118>(best);
            best = dpp_max_u64<0x142>(best);
            best = dpp_max_u64<0x143>(best);
            ckv  = __uint_as_float((unsigned)__builtin_amdgcn_readlane((int)(best >> 32), 63));
            cklo = (unsigned)__builtin_amdgcn_readlane((int)(best & 0xffffffffull), 63);
        }
        if (lane == 0)
            atomicMax(&s_slot[cur],
                      ((unsigned long long)__float_as_uint(ckv) << 32) | cklo);
        __syncthreads();                                 // the ONLY barrier per iter
        const unsigned long long k = s_slot[cur];        // b64 broadcast read
        const int ix = ~(int)(unsigned)(k & 0xffffffffull);  // original point index
        lx = sx[ix]; ly = sy[ix]; lz = sz[ix];           // LDS broadcast gather
        if (tid == 0) {
            s_hist[3*i+0] = lx; s_hist[3*i+1] = ly; s_hist[3*i+2] = lz;
        }
        cur = nxt;                                       // rotate slot indices
        nxt = nxt + 1; if (nxt == 3) nxt = 0;
    }
    __syncthreads();                                     // last hist write visible
    // coalesced flush of the selected-coordinate history
    float* nw = new_xyz + (size_t)b * NS * 3;
    float* ow = out_newxyz + (size_t)b * NS * 3;
    for (int t = tid; t < NS * 3; t += 1024) {
        float v = s_hist[t];
        nw[t] = v; ow[t] = v;
    }
}

// ============================================================================
// 3) Ball query: one wave per (b,s) query. First 32 smallest in-ball indices,
//    pad with first. r2 must be float(0.2*0.2) = 0.0399999991 (not 0.2f*0.2f).
// ============================================================================
__global__ __launch_bounds__(256) void ballquery_kernel(const float* __restrict__ xyz,
    const float* __restrict__ new_xyz, int* __restrict__ idx)
{
#pragma clang fp contract(off)
    const int q = blockIdx.x * 4 + (threadIdx.x >> 6);
    const int lane = threadIdx.x & 63;
    const int b = q >> 11;
    const float r2 = (float)(0.2 * 0.2);
    const float* xb = xyz + (size_t)b * NN * 3;
    const float* nx = new_xyz + (size_t)q * 3;
    float qx = nx[0], qy = nx[1], qz = nx[2];
    int cnt = 0, first = -1;
    int* out = idx + (size_t)q * NK;
    for (int base = 0; base < NN; base += 64) {
        int p = base + lane;
        float x = xb[p*3+0], y = xb[p*3+1], z = xb[p*3+2];
        float dx = qx - x, dy = qy - y, dz = qz - z;
        float d2 = (dx*dx + dy*dy) + dz*dz;
        bool in = d2 < r2;
        unsigned long long m = __ballot(in);
        if (m) {
            if (first < 0) first = base + __builtin_ctzll(m);
            if (in) {
                int rank = cnt + __popcll(m & ((1ull << lane) - 1ull));
                if (rank < NK) out[rank] = p;
            }
            cnt += __popcll(m);
            if (cnt >= NK) break;
        }
    }
    for (int k = cnt + lane; k < NK; k += 64) out[k] = first;  // cnt>=1 always
}

// ============================================================================
// 4) Layer 1: h1 = W1(64x67) @ g. v2f packed FMAs; fp32 kept to bound
//    cumulative bf16 error. Plain store (R14 lesson: fusing stats here costs
//    more VALU than the 13us h1 re-read it saves — per-value DPP reduces,
//    unlike layer2/3's amortized tile epilogues).
// ============================================================================
__global__ __launch_bounds__(256, 2) void layer1_kernel(const float* __restrict__ xyz,
    const float* __restrict__ new_xyz, const int* __restrict__ idx,
    const float* __restrict__ ft, const float* __restrict__ W1,
    unsigned short* __restrict__ h1)
{
    const int col = blockIdx.x * 256 + threadIdx.x;
    const int b = col >> 16;
    const int s = (col >> 5) & 2047;
    const int p = idx[col];
    v2f g[34];
    float* gf = (float*)g;
    {
        const float* nx = new_xyz + ((size_t)(b * NS + s)) * 3;
        const float* xp = xyz + ((size_t)(b * NN + p)) * 3;
        gf[0] = xp[0] - nx[0]; gf[1] = xp[1] - nx[1]; gf[2] = xp[2] - nx[2];
    }
    const float4* fp = (const float4*)(ft + ((size_t)(b * NN + p)) * NC);
#pragma unroll
    for (int c4 = 0; c4 < 16; ++c4) {
        float4 v = fp[c4];
        gf[3 + 4*c4 + 0] = v.x; gf[3 + 4*c4 + 1] = v.y;
        gf[3 + 4*c4 + 2] = v.z; gf[3 + 4*c4 + 3] = v.w;
    }
    gf[67] = 0.f;
    uint4* dst = (uint4*)(h1 + (size_t)col * 64);
#pragma unroll
    for (int half = 0; half < 2; ++half) {
        float h[32];
#pragma unroll 4
        for (int o16 = 0; o16 < 32; ++o16) {
            const float* w = W1 + (half*32 + o16) * 67;
            v2f acc; acc.x = 0.f; acc.y = 0.f;
#pragma unroll
            for (int k = 0; k < 33; ++k) {
                v2f wv; wv.x = w[2*k]; wv.y = w[2*k+1];
                acc = wv * g[k] + acc;                    // v_pk_fma_f32
            }
            h[o16] = fmaf(w[66], gf[66], acc.x + acc.y);
        }
#pragma unroll
        for (int k = 0; k < 4; ++k) {
            uint4 v;
            v.x = (unsigned)f2bf(h[8*k+0]) | ((unsigned)f2bf(h[8*k+1]) << 16);
            v.y = (unsigned)f2bf(h[8*k+2]) | ((unsigned)f2bf(h[8*k+3]) << 16);
            v.z = (unsigned)f2bf(h[8*k+4]) | ((unsigned)f2bf(h[8*k+5]) << 16);
            v.w = (unsigned)f2bf(h[8*k+6]) | ((unsigned)f2bf(h[8*k+7]) << 16);
            dst[half*4 + k] = v;
        }
    }
}

// ============================================================================
// 5) Stats pass over bf16 h1: per-channel sum / sumsq.
// ============================================================================
__global__ __launch_bounds__(256) void stats_kernel(const unsigned short* __restrict__ h,
    float* __restrict__ sums)
{
    __shared__ float ls[64], lq[64];
    const int tid = threadIdx.x;
    if (tid < 64) { ls[tid] = 0.f; lq[tid] = 0.f; }
    __syncthreads();
    float s[8] = {0,0,0,0,0,0,0,0}, q[8] = {0,0,0,0,0,0,0,0};
    const int gt = blockIdx.x * 256 + tid;
    const int G = gridDim.x * 256;            // multiple of 8 -> channel phase fixed
    const uint4* src = (const uint4*)h;
    const int nvec = NCOL * 8;                 // uint4s (8 bf16 each)
    for (int i = gt; i < nvec; i += G) {
        uint4 v = src[i];
        float f0 = bf2f(v.x & 0xffffu), f1 = bf2f(v.x >> 16);
        float f2 = bf2f(v.y & 0xffffu), f3 = bf2f(v.y >> 16);
        float f4 = bf2f(v.z & 0xffffu), f5 = bf2f(v.z >> 16);
        float f6 = bf2f(v.w & 0xffffu), f7 = bf2f(v.w >> 16);
        s[0] += f0; q[0] = fmaf(f0, f0, q[0]);
        s[1] += f1; q[1] = fmaf(f1, f1, q[1]);
        s[2] += f2; q[2] = fmaf(f2, f2, q[2]);
        s[3] += f3; q[3] = fmaf(f3, f3, q[3]);
        s[4] += f4; q[4] = fmaf(f4, f4, q[4]);
        s[5] += f5; q[5] = fmaf(f5, f5, q[5]);
        s[6] += f6; q[6] = fmaf(f6, f6, q[6]);
        s[7] += f7; q[7] = fmaf(f7, f7, q[7]);
    }
    const int obase = (tid & 7) * 8;
#pragma unroll
    for (int j = 0; j < 8; ++j) {
        atomicAdd(&ls[obase + j], s[j]);
        atomicAdd(&lq[obase + j], q[j]);
    }
    __syncthreads();
    if (tid < 64) {
        atomicAdd(&sums[tid*2+0], ls[tid]);
        atomicAdd(&sums[tid*2+1], lq[tid]);
    }
}

// ============================================================================
// 6) Finalize BN params. Layout: ab[c] = a_c (scale), ab[nch+c] = b_c (shift)
//    so the apply step can use packed v2f math.
// ============================================================================
__global__ void finalize_kernel(const float* __restrict__ sums,
    const float* __restrict__ gamma, const float* __restrict__ beta,
    float* __restrict__ ab, int nch)
{
    int c = threadIdx.x;
    if (c < nch) {
        const float invM = 1.0f / 524288.0f;
        float mu = sums[c*2] * invM;
        float var = sums[c*2+1] * invM - mu * mu;
        float a = gamma[c] / sqrtf(var + 1e-5f);
        ab[c] = a;
        ab[nch + c] = fmaf(-mu, a, beta[c]);
    }
}

// ============================================================================
// 7) Layer 2 via MFMA + FUSED stats2 (R13, proven): h2 = W2 @ relu(BN1(h1)),
//    stats of the ROUNDED stored values accumulated in the epilogue.
// ============================================================================
__global__ __launch_bounds__(256, 2) void layer2_kernel(const unsigned short* __restrict__ h1,
    const float* __restrict__ ab1, const float* __restrict__ W2,
    unsigned short* __restrict__ h2, float* __restrict__ sums2)
{
    __shared__ float ls[64], lq[64];
    const int tid = threadIdx.x;
    if (tid < 64) { ls[tid] = 0.f; lq[tid] = 0.f; }
    __syncthreads();
    const int lane = tid & 63;
    const int col0 = lane & 15;                          // n (col in tile) / m (row of A)
    const int rg   = lane >> 4;                          // k-group (inputs), row-group (D)
    const int wglob = blockIdx.x * 4 + (tid >> 6);       // 0..8191

    float sums[16], sqs[16];                             // [rt*4 + r]
#pragma unroll
    for (int t = 0; t < 16; ++t) { sums[t] = 0.f; sqs[t] = 0.f; }

    for (int g = wglob * 2; g < wglob * 2 + 2; ++g) {    // 2 (b,s)-groups per wave
        // ---- build B fragments for both 16-col tiles of this group ----
        bf16x8 Bf[2][2];                                 // [tile][kh]
#pragma unroll
        for (int t = 0; t < 2; ++t) {
            const int col = g * 32 + t * 16 + col0;
            const unsigned short* hp = h1 + (size_t)col * 64 + rg * 8;
#pragma unroll
            for (int kh = 0; kh < 2; ++kh) {
                uint4 hv = *(const uint4*)(hp + kh * 32);
                const float* ap = ab1 + kh * 32 + rg * 8;
                float4 a0 = *(const float4*)ap;
                float4 a1 = *(const float4*)(ap + 4);
                float4 b0 = *(const float4*)(ap + 64);
                float4 b1 = *(const float4*)(ap + 68);
                bf16x8 f;
                f[0] = (short)f2bf(fmaxf(fmaf(a0.x, bf2f(hv.x & 0xffffu), b0.x), 0.f));
                f[1] = (short)f2bf(fmaxf(fmaf(a0.y, bf2f(hv.x >> 16),     b0.y), 0.f));
                f[2] = (short)f2bf(fmaxf(fmaf(a0.z, bf2f(hv.y & 0xffffu), b0.z), 0.f));
                f[3] = (short)f2bf(fmaxf(fmaf(a0.w, bf2f(hv.y >> 16),     b0.w), 0.f));
                f[4] = (short)f2bf(fmaxf(fmaf(a1.x, bf2f(hv.z & 0xffffu), b1.x), 0.f));
                f[5] = (short)f2bf(fmaxf(fmaf(a1.y, bf2f(hv.z >> 16),     b1.y), 0.f));
                f[6] = (short)f2bf(fmaxf(fmaf(a1.z, bf2f(hv.w & 0xffffu), b1.z), 0.f));
                f[7] = (short)f2bf(fmaxf(fmaf(a1.w, bf2f(hv.w >> 16),     b1.w), 0.f));
                Bf[t][kh] = f;
            }
        }
        // ---- 4 row-tiles of 16 output channels (64 outputs total) ----
#pragma unroll
        for (int rt = 0; rt < 4; ++rt) {
            f32x4 acc0 = {0.f, 0.f, 0.f, 0.f};
            f32x4 acc1 = {0.f, 0.f, 0.f, 0.f};
#pragma unroll
            for (int kh = 0; kh < 2; ++kh) {
                const float* wp = W2 + (size_t)(rt * 16 + col0) * 64 + kh * 32 + rg * 8;
                float4 w0 = *(const float4*)wp;
                float4 w1 = *(const float4*)(wp + 4);
                bf16x8 Af;
                Af[0] = (short)f2bf(w0.x); Af[1] = (short)f2bf(w0.y);
                Af[2] = (short)f2bf(w0.z); Af[3] = (short)f2bf(w0.w);
                Af[4] = (short)f2bf(w1.x); Af[5] = (short)f2bf(w1.y);
                Af[6] = (short)f2bf(w1.z); Af[7] = (short)f2bf(w1.w);
                acc0 = __builtin_amdgcn_mfma_f32_16x16x32_bf16(Af, Bf[0][kh], acc0, 0, 0, 0);
                acc1 = __builtin_amdgcn_mfma_f32_16x16x32_bf16(Af, Bf[1][kh], acc1, 0, 0, 0);
            }
            // store rounded bf16 + accumulate stats of the ROUNDED values
            unsigned u00 = f2bf(acc0[0]), u01 = f2bf(acc0[1]);
            unsigned u02 = f2bf(acc0[2]), u03 = f2bf(acc0[3]);
            unsigned u10 = f2bf(acc1[0]), u11 = f2bf(acc1[1]);
            unsigned u12 = f2bf(acc1[2]), u13 = f2bf(acc1[3]);
            {
                const int col = g * 32 + 0 * 16 + col0;
                uint2 v; v.x = u00 | (u01 << 16); v.y = u02 | (u03 << 16);
                *(uint2*)(h2 + (size_t)col * 64 + rt * 16 + rg * 4) = v;
            }
            {
                const int col = g * 32 + 1 * 16 + col0;
                uint2 v; v.x = u10 | (u11 << 16); v.y = u12 | (u13 << 16);
                *(uint2*)(h2 + (size_t)col * 64 + rt * 16 + rg * 4) = v;
            }
#pragma unroll
            for (int r = 0; r < 4; ++r) {
                float r0 = bf2f(r == 0 ? u00 : r == 1 ? u01 : r == 2 ? u02 : u03);
                float r1 = bf2f(r == 0 ? u10 : r == 1 ? u11 : r == 2 ? u12 : u13);
                sums[rt*4 + r] += r0 + r1;
                sqs[rt*4 + r]  = fmaf(r0, r0, fmaf(r1, r1, sqs[rt*4 + r]));
            }
        }
    }
    // ---- channel sums: reduce over cols (16-lane rows), then LDS -> global
#pragma unroll
    for (int t = 0; t < 16; ++t) {
        float sm = sums[t], sq = sqs[t];
        sm = dpp_add_f32<0x111>(sm); sq = dpp_add_f32<0x111>(sq);
        sm = dpp_add_f32<0x112>(sm); sq = dpp_add_f32<0x112>(sq);
        sm = dpp_add_f32<0x114>(sm); sq = dpp_add_f32<0x114>(sq);
        sm = dpp_add_f32<0x118>(sm); sq = dpp_add_f32<0x118>(sq);
        if (col0 == 15) {
            const int o = (t >> 2) * 16 + rg * 4 + (t & 3);
            atomicAdd(&ls[o], sm);
            atomicAdd(&lq[o], sq);
        }
    }
    __syncthreads();
    if (tid < 64) {
        atomicAdd(&sums2[tid*2+0], ls[tid]);
        atomicAdd(&sums2[tid*2+1], lq[tid]);
    }
}

// ============================================================================
// 8) Layer 3 via MFMA (bf16 in, f32 acc): h3 = W3(128x64) @ relu(BN2(h2)).
//    R10/R11 version (proven).
// ============================================================================
__global__ __launch_bounds__(256, 2) void layer3_kernel(const unsigned short* __restrict__ h2,
    const float* __restrict__ ab2, const float* __restrict__ W3,
    float* __restrict__ hmax, float* __restrict__ hmin, float* __restrict__ sums3)
{
    __shared__ float ls[128], lq[128];
    const int tid = threadIdx.x;
    if (tid < 128) { ls[tid] = 0.f; lq[tid] = 0.f; }
    __syncthreads();
    const int lane = tid & 63;
    const int col0 = lane & 15;                          // n (col in tile) / m (row of A)
    const int rg   = lane >> 4;                          // k-group (inputs), row-group (D)
    const int wglob = blockIdx.x * 4 + (tid >> 6);       // 0..8191

    float sums[32], sqs[32];                             // [rt][reg]
#pragma unroll
    for (int t = 0; t < 32; ++t) { sums[t] = 0.f; sqs[t] = 0.f; }

    for (int g = wglob * 2; g < wglob * 2 + 2; ++g) {    // 2 (b,s)-groups per wave
        // ---- build B fragments for both 16-col tiles of this group ----
        bf16x8 Bf[2][2];                                 // [tile][kh]
#pragma unroll
        for (int t = 0; t < 2; ++t) {
            const int col = g * 32 + t * 16 + col0;
            const unsigned short* hp = h2 + (size_t)col * 64 + rg * 8;
#pragma unroll
            for (int kh = 0; kh < 2; ++kh) {
                uint4 hv = *(const uint4*)(hp + kh * 32);
                const float* ap = ab2 + kh * 32 + rg * 8;
                float4 a0 = *(const float4*)ap;
                float4 a1 = *(const float4*)(ap + 4);
                float4 b0 = *(const float4*)(ap + 64);
                float4 b1 = *(const float4*)(ap + 68);
                bf16x8 f;
                f[0] = (short)f2bf(fmaxf(fmaf(a0.x, bf2f(hv.x & 0xffffu), b0.x), 0.f));
                f[1] = (short)f2bf(fmaxf(fmaf(a0.y, bf2f(hv.x >> 16),     b0.y), 0.f));
                f[2] = (short)f2bf(fmaxf(fmaf(a0.z, bf2f(hv.y & 0xffffu), b0.z), 0.f));
                f[3] = (short)f2bf(fmaxf(fmaf(a0.w, bf2f(hv.y >> 16),     b0.w), 0.f));
                f[4] = (short)f2bf(fmaxf(fmaf(a1.x, bf2f(hv.z & 0xffffu), b1.x), 0.f));
                f[5] = (short)f2bf(fmaxf(fmaf(a1.y, bf2f(hv.z >> 16),     b1.y), 0.f));
                f[6] = (short)f2bf(fmaxf(fmaf(a1.z, bf2f(hv.w & 0xffffu), b1.z), 0.f));
                f[7] = (short)f2bf(fmaxf(fmaf(a1.w, bf2f(hv.w >> 16),     b1.w), 0.f));
                Bf[t][kh] = f;
            }
        }
        // ---- 8 row-tiles of 16 output channels ----
#pragma unroll
        for (int rt = 0; rt < 8; ++rt) {
            f32x4 acc0 = {0.f, 0.f, 0.f, 0.f};
            f32x4 acc1 = {0.f, 0.f, 0.f, 0.f};
#pragma unroll
            for (int kh = 0; kh < 2; ++kh) {
                const float* wp = W3 + (size_t)(rt * 16 + col0) * 64 + kh * 32 + rg * 8;
                float4 w0 = *(const float4*)wp;
                float4 w1 = *(const float4*)(wp + 4);
                bf16x8 Af;
                Af[0] = (short)f2bf(w0.x); Af[1] = (short)f2bf(w0.y);
                Af[2] = (short)f2bf(w0.z); Af[3] = (short)f2bf(w0.w);
                Af[4] = (short)f2bf(w1.x); Af[5] = (short)f2bf(w1.y);
                Af[6] = (short)f2bf(w1.z); Af[7] = (short)f2bf(w1.w);
                acc0 = __builtin_amdgcn_mfma_f32_16x16x32_bf16(Af, Bf[0][kh], acc0, 0, 0, 0);
                acc1 = __builtin_amdgcn_mfma_f32_16x16x32_bf16(Af, Bf[1][kh], acc1, 0, 0, 0);
            }
#pragma unroll
            for (int r = 0; r < 4; ++r) {
                float v0 = acc0[r], v1 = acc1[r];
                sums[rt*4 + r] += v0 + v1;
                sqs[rt*4 + r]  = fmaf(v0, v0, fmaf(v1, v1, sqs[rt*4 + r]));
                float mx = fmaxf(v0, v1);
                float mn = fminf(v0, v1);
                mx = dpp_max_f32<0x111>(mx); mn = dpp_min_f32<0x111>(mn);
                mx = dpp_max_f32<0x112>(mx); mn = dpp_min_f32<0x112>(mn);
                mx = dpp_max_f32<0x114>(mx); mn = dpp_min_f32<0x114>(mn);
                mx = dpp_max_f32<0x118>(mx); mn = dpp_min_f32<0x118>(mn);
                if (col0 == 15) {                        // lane15 of each 16-lane row
                    const int o = rt * 16 + rg * 4 + r;
                    hmax[(size_t)o * 16384 + g] = mx;
                    hmin[(size_t)o * 16384 + g] = mn;
                }
            }
        }
    }
    // ---- channel sums: reduce over cols (16-lane rows), then LDS -> global
#pragma unroll
    for (int t = 0; t < 32; ++t) {
        float sm = sums[t], sq = sqs[t];
        sm = dpp_add_f32<0x111>(sm); sq = dpp_add_f32<0x111>(sq);
        sm = dpp_add_f32<0x112>(sm); sq = dpp_add_f32<0x112>(sq);
        sm = dpp_add_f32<0x114>(sm); sq = dpp_add_f32<0x114>(sq);
        sm = dpp_add_f32<0x118>(sm); sq = dpp_add_f32<0x118>(sq);
        if (col0 == 15) {
            const int o = (t >> 2) * 16 + rg * 4 + (t & 3);
            atomicAdd(&ls[o], sm);
            atomicAdd(&lq[o], sq);
        }
    }
    __syncthreads();
    if (tid < 128) {
        atomicAdd(&sums3[tid*2+0], ls[tid]);
        atomicAdd(&sums3[tid*2+1], lq[tid]);
    }
}

// ============================================================================
// 9) Final: feats[b,o,s] = relu(a3*(a3>=0 ? max : min) + c3)
// ============================================================================
__global__ __launch_bounds__(256) void final_kernel(const float* __restrict__ hmax,
    const float* __restrict__ hmin, const float* __restrict__ ab3,
    float* __restrict__ out)
{
    const int t = blockIdx.x * 256 + threadIdx.x;   // (b,o,s), s fastest
    const int s = t & 2047;
    const int o = (t >> 11) & 127;
    const int b = t >> 18;
    const int q = (b << 11) + s;
    float a = ab3[o], c = ab3[128 + o];
    float h = (a >= 0.f) ? hmax[(size_t)o * 16384 + q] : hmin[(size_t)o * 16384 + q];
    out[t] = fmaxf(fmaf(a, h, c), 0.f);
}

// ============================================================================
extern "C" void kernel_launch(void* const* d_in, const int* in_sizes, int n_in,
                              void* d_out, int out_size, void* d_ws, size_t ws_size,
                              hipStream_t stream) {
    (void)in_sizes; (void)n_in; (void)out_size; (void)ws_size;
    const float* xyz      = (const float*)d_in[0];
    const float* features = (const float*)d_in[1];
    const float* W1 = (const float*)d_in[2];
    const float* g1 = (const float*)d_in[3];
    const float* b1 = (const float*)d_in[4];
    const float* W2 = (const float*)d_in[5];
    const float* g2 = (const float*)d_in[6];
    const float* b2 = (const float*)d_in[7];
    const float* W3 = (const float*)d_in[8];
    const float* g3 = (const float*)d_in[9];
    const float* b3 = (const float*)d_in[10];

    char* ws = (char*)d_ws;
    float*          new_xyz = (float*)(ws + 0);                  // 196608 B
    int*            idx     = (int*)(ws + 196608);               // 2097152 B
    float*          ft      = (float*)(ws + 2293760);            // 16777216 B
    unsigned short* h1      = (unsigned short*)(ws + 19070976);  // 67108864 B
    unsigned short* h2      = (unsigned short*)(ws + 86179840);  // 67108864 B
    float*          hmax    = (float*)(ws + 153288704);          // 8388608 B
    float*          hmin    = (float*)(ws + 161677312);          // 8388608 B
    float*          sums    = (float*)(ws + 170065920);          // 2048 B (zeroed)
    float*          ab      = (float*)(ws + 170067968);          // 2048 B
    float* sums1 = sums;        float* ab1 = ab;
    float* sums2 = sums + 128;  float* ab2 = ab + 128;
    float* sums3 = sums + 256;  float* ab3 = ab + 256;

    // sorted point array (float4 x,y,z,idx) lives in h1's space: h1 is only
    // written by layer1 AFTER fps completes (stream order), so no conflict.
    float4* sorted = (float4*)h1;                 // NB*NN*16 = 1 MB

    float* out_newxyz = (float*)d_out;            // B*NS*3 = 49152 floats
    float* out_feats  = (float*)d_out + 49152;    // B*128*NS floats

    hipMemsetAsync(sums, 0, 2048, stream);

    sort_kernel<<<NB, 1024, 0, stream>>>(xyz, sorted);
    // fps (blocks 0-7) + transpose (blocks 8-263) fused
    fps_tr_kernel<<<NB + 256, 1024, 0, stream>>>(xyz, sorted, new_xyz, out_newxyz,
                                                 features, ft);
    ballquery_kernel<<<(NB*NS)/4, 256, 0, stream>>>(xyz, new_xyz, idx);
    layer1_kernel<<<NCOL/256, 256, 0, stream>>>(xyz, new_xyz, idx, ft, W1, h1);
    stats_kernel<<<1024, 256, 0, stream>>>(h1, sums1);
    finalize_kernel<<<1, 128, 0, stream>>>(sums1, g1, b1, ab1, 64);
    layer2_kernel<<<2048, 256, 0, stream>>>(h1, ab1, W2, h2, sums2);   // stats2 fused
    finalize_kernel<<<1, 128, 0, stream>>>(sums2, g2, b2, ab2, 64);
    layer3_kernel<<<2048, 256, 0, stream>>>(h2, ab2, W3, hmax, hmin, sums3);
    finalize_kernel<<<1, 128, 0, stream>>>(sums3, g3, b3, ab3, 128);
    final_kernel<<<(NB*128*NS)/256, 256, 0, stream>>>(hmax, hmin, ab3, out_feats);
}